// Round 8
// baseline (164.906 us; speedup 1.0000x reference)
//
#include <hip/hip_runtime.h>
#include <hip/hip_bf16.h>
#include <float.h>

// RigidityLoss: M=16384 gathered points, brute-force KNN (K=8) + loss.
// R7: 32x32x16 f16 MFMA computes t[r][c] = sq_c - 2*dot(q_r,p_c) directly
// (sq folded in via k=3: A[r][3]=1, B[3][c]=sq_c). Per 1024-eval tile the
// VALU cost is only 16 pack + 16 min + idx. Stage 1 keeps top-1 per
// (row, 32-class x 8-split bin) and dumps all 256 bins/row raw to ws —
// no extraction. Stage 2: one wave per row, top-3/lane insert over its
// 4 bins, 8-round shfl extraction of the global top-8, exact-f32 loss.

#define MPTS 16384
#define KNN  8
#define CDIM 16
#define LAMW 0.1f
#define EPSV 1e-6f

#define NSPLIT 8
#define CSPL  (MPTS/NSPLIT)    // 2048 candidates per split
#define TILES (CSPL/32)        // 64 MFMA tiles per wave
#define NBINS (NSPLIT*32)      // 256 bins per row

#define MED3 __builtin_amdgcn_fmed3f
typedef __attribute__((ext_vector_type(8)))  _Float16 f16x8;
typedef __attribute__((ext_vector_type(16))) float    f32x16;

__global__ __launch_bounds__(256) void k_gather(
    const float* __restrict__ canon, const float* __restrict__ trans,
    const int* __restrict__ indice, float4* __restrict__ c4,
    _Float16* __restrict__ bf16b, _Float16* __restrict__ af16b,
    float* __restrict__ acc)
{
    int t = blockIdx.x * 256 + threadIdx.x;
    if (t == 0) { acc[0] = 0.f; acc[1] = 0.f; }
    if (t < MPTS) {
        int j = indice[t];
        float x = canon[3*j+0] + trans[3*j+0];
        float y = canon[3*j+1] + trans[3*j+1];
        float z = canon[3*j+2] + trans[3*j+2];
        float sq = fmaf(x, x, fmaf(y, y, z*z));
        c4[t] = make_float4(-2.f*x, -2.f*y, -2.f*z, sq);   // exact f32 blob
        f16x8 aa = {};
        aa[0] = (_Float16)(-2.f*x); aa[1] = (_Float16)(-2.f*y);
        aa[2] = (_Float16)(-2.f*z); aa[3] = (_Float16)1.0f;
        *(f16x8*)(af16b + (size_t)t*8) = aa;
        f16x8 bb = {};
        bb[0] = (_Float16)x; bb[1] = (_Float16)y; bb[2] = (_Float16)z;
        bb[3] = (_Float16)sq;
        *(f16x8*)(bf16b + (size_t)t*8) = bb;
    }
}

__global__ __launch_bounds__(256, 6) void k_knn(
    const _Float16* __restrict__ bf16b, const _Float16* __restrict__ af16b,
    float* __restrict__ keys)
{
    const int tid  = threadIdx.x;
    const int lane = tid & 63;
    const int wid  = (blockIdx.x << 2) | (tid >> 6);   // 0..4095
    const int rowtile = wid >> 3;                      // 0..511 (wid / NSPLIT)
    const int split   = wid & (NSPLIT-1);
    const int rowbase = rowtile * 32;
    const int cbeg    = split * CSPL;
    const int cls     = lane & 31;

    // A fragment: lane l<32 -> row (rowbase+l), k=0..7; lanes>=32 (k=8..15) zero.
    f16x8 afrag = *(const f16x8*)(af16b + (size_t)(rowbase + cls) * 8);
    if (lane >= 32) { f16x8 zz = {}; afrag = zz; }
    f32x16 zero16 = {};

    // B fragment source: lane l holds col (l&31), k-half (l>>5); upper-half
    // garbage is annihilated by A's zero k=8..15. All lanes read the l&31
    // address -> same cache lines as lower half.
    const _Float16* bptr = bf16b + (size_t)(cbeg + cls) * 8;
    const unsigned  HMASK = 0xFFFFC000u;
    const unsigned  ivb   = (unsigned)(cbeg + cls);

    // 16 row-states (g -> row (g&3)+8*(g>>2)+4*(lane>>5)), top-1 each
    float e0=FLT_MAX,e1=FLT_MAX,e2=FLT_MAX,e3=FLT_MAX;
    float e4=FLT_MAX,e5=FLT_MAX,e6=FLT_MAX,e7=FLT_MAX;
    float e8=FLT_MAX,e9=FLT_MAX,e10=FLT_MAX,e11=FLT_MAX;
    float e12=FLT_MAX,e13=FLT_MAX,e14=FLT_MAX,e15=FLT_MAX;

    for (int tile = 0; tile < TILES; ++tile) {
        f16x8 b = *(const f16x8*)(bptr + (size_t)tile * 256);  // 32 cands fwd
        f32x16 dv = __builtin_amdgcn_mfma_f32_32x32x16_f16(afrag, b, zero16, 0, 0, 0);
        unsigned iv = ivb + (unsigned)(tile * 32);
#define STEP(G, EG) { float kf = __uint_as_float((__float_as_uint(dv[G]) & HMASK) | iv); \
                      EG = fminf(EG, kf); }
        STEP(0,e0)  STEP(1,e1)  STEP(2,e2)  STEP(3,e3)
        STEP(4,e4)  STEP(5,e5)  STEP(6,e6)  STEP(7,e7)
        STEP(8,e8)  STEP(9,e9)  STEP(10,e10) STEP(11,e11)
        STEP(12,e12) STEP(13,e13) STEP(14,e14) STEP(15,e15)
#undef STEP
    }

    // raw dump: keys[row][split*32 + cls], row = (g&3)+8*(g>>2)+4*(lane>>5)
    float* kb = keys + ((size_t)(rowbase + (lane >> 5) * 4)) * NBINS
                     + (size_t)split * 32 + cls;
#define ST(ROW, EG) kb[(size_t)(ROW) * NBINS] = EG;
    ST(0,e0)  ST(1,e1)  ST(2,e2)  ST(3,e3)
    ST(8,e4)  ST(9,e5)  ST(10,e6) ST(11,e7)
    ST(16,e8) ST(17,e9) ST(18,e10) ST(19,e11)
    ST(24,e12) ST(25,e13) ST(26,e14) ST(27,e15)
#undef ST
}

__global__ __launch_bounds__(256) void k_merge_loss(
    const float4* __restrict__ c4, const float* __restrict__ keys,
    const int* __restrict__ indice, const float* __restrict__ motion,
    const float* __restrict__ fdc, float* __restrict__ acc)
{
    __shared__ float rS[4], rM[4];
    const int tid  = threadIdx.x;
    const int lane = tid & 63;
    const int wv   = tid >> 6;
    const int row  = blockIdx.x * 4 + wv;

    // load this row's 256 bins: 1 float4 per lane
    const float4* kp = (const float4*)(keys + (size_t)row * NBINS);
    float4 vb = kp[lane];

    // per-lane top-3 of its 4 bins
    float e0=FLT_MAX, e1=FLT_MAX, e2=FLT_MAX;
#define INS(V) { e2=MED3(e1,e2,V); e1=MED3(e0,e1,V); e0=fminf(e0,V); }
    INS(vb.x) INS(vb.y) INS(vb.z) INS(vb.w)
#undef INS

    // extract 8 smallest over 64 lanes; lane s ends holding s-th smallest
    float kres = FLT_MAX;
    #pragma unroll
    for (int s = 0; s < KNN; ++s) {
        float m = e0;
        m = fminf(m, __shfl_xor(m, 1));
        m = fminf(m, __shfl_xor(m, 2));
        m = fminf(m, __shfl_xor(m, 4));
        m = fminf(m, __shfl_xor(m, 8));
        m = fminf(m, __shfl_xor(m, 16));
        m = fminf(m, __shfl_xor(m, 32));
        bool mine = (e0 == m);            // keys unique (idx in low bits)
        kres = (lane == s) ? m : kres;
        e0 = mine ? e1 : e0;
        e1 = mine ? e2 : e1;
        e2 = mine ? FLT_MAX : e2;
    }

    // ---- loss: lanes 0..7 handle neighbors 0..7 of this row ----
    float4 rc = c4[row];
    const float qx=-0.5f*rc.x, qy=-0.5f*rc.y, qz=-0.5f*rc.z, qq=rc.w;

    int jk = (int)(__float_as_uint(kres) & 0x3FFFu);
    float4 nc = c4[jk];
    float te  = fmaf(qx, nc.x, fmaf(qy, nc.y, fmaf(qz, nc.z, nc.w)));
    float d2k = qq + te;                   // exact squared distance

    float xn = -0.5f*nc.x, yn = -0.5f*nc.y, zn = -0.5f*nc.z;
    float sx = xn, sy = yn, sz = zn;
    sx += __shfl_xor(sx, 1); sx += __shfl_xor(sx, 2); sx += __shfl_xor(sx, 4);
    sy += __shfl_xor(sy, 1); sy += __shfl_xor(sy, 2); sy += __shfl_xor(sy, 4);
    sz += __shfl_xor(sz, 1); sz += __shfl_xor(sz, 2); sz += __shfl_xor(sz, 4);

    float surf = 0.f, simv = 0.f;
    if (lane < KNN) {
        if (lane == 0) {
            float dx = qx - sx * 0.125f + EPSV;
            float dy = qy - sy * 0.125f + EPSV;
            float dz = qz - sz * 0.125f + EPSV;
            surf = sqrtf(fmaf(dx, dx, fmaf(dy, dy, dz * dz)));
        }
        int irow = indice[row];
        int inb  = indice[jk];
        float c0v = fdc[3*irow+0] - fdc[3*inb+0] + EPSV;
        float c1v = fdc[3*irow+1] - fdc[3*inb+1] + EPSV;
        float c2v = fdc[3*irow+2] - fdc[3*inb+2] + EPSV;
        float cd2 = fmaf(c0v, c0v, fmaf(c1v, c1v, c2v * c2v));
        float w = __expf(-LAMW * fmaf(d2k, d2k, cd2));   // dist_w * color_w

        const float4* mr4 = (const float4*)(motion + CDIM * irow);
        const float4* mn4 = (const float4*)(motion + CDIM * inb);
        float s = 0.f;
        #pragma unroll
        for (int c = 0; c < CDIM/4; ++c) {
            float4 A = mr4[c], B = mn4[c];
            float g0 = A.x-B.x+EPSV, g1 = A.y-B.y+EPSV;
            float g2 = A.z-B.z+EPSV, g3 = A.w-B.w+EPSV;
            s = fmaf(g0,g0, fmaf(g1,g1, fmaf(g2,g2, fmaf(g3,g3, s))));
        }
        simv = w * sqrtf(s);
    }

    // ---- block reduction ----
    float aS = surf, aM = simv;
    #pragma unroll
    for (int m = 1; m <= 32; m <<= 1) {
        aS += __shfl_xor(aS, m);
        aM += __shfl_xor(aM, m);
    }
    if (lane == 0) { rS[wv] = aS; rM[wv] = aM; }
    __syncthreads();
    if (tid == 0) {
        float tS = 0.f, tM = 0.f;
        #pragma unroll
        for (int w2 = 0; w2 < 4; ++w2) { tS += rS[w2]; tM += rM[w2]; }
        atomicAdd(&acc[0], tS);
        atomicAdd(&acc[1], tM);
    }
}

__global__ void k_final(const float* __restrict__ acc, float* __restrict__ out)
{
    out[0] = acc[0] * (1.0f / MPTS) + acc[1] * (1.0f / (MPTS * KNN));
}

extern "C" void kernel_launch(void* const* d_in, const int* in_sizes, int n_in,
                              void* d_out, int out_size, void* d_ws, size_t ws_size,
                              hipStream_t stream)
{
    const float* canon  = (const float*)d_in[0];
    const float* trans  = (const float*)d_in[1];
    const float* motion = (const float*)d_in[2];
    const float* fdc    = (const float*)d_in[3];
    const int*   indice = (const int*)d_in[4];
    float* out = (float*)d_out;

    char* ws = (char*)d_ws;
    float*     acc   = (float*)ws;                          // @0
    float4*    c4    = (float4*)(ws + 4096);                // 256 KB
    _Float16*  af16b = (_Float16*)(ws + 4096 + 262144);     // 256 KB
    _Float16*  bf16b = (_Float16*)(ws + 4096 + 2*262144);   // 256 KB
    float*     keys  = (float*)(ws + 4096 + 3*262144);      // M*256*4 = 16 MB

    k_gather<<<MPTS/256, 256, 0, stream>>>(canon, trans, indice, c4, bf16b, af16b, acc);
    k_knn<<<(MPTS/32)*NSPLIT/4, 256, 0, stream>>>(bf16b, af16b, keys);
    k_merge_loss<<<MPTS/4, 256, 0, stream>>>(c4, keys, indice, motion, fdc, acc);
    k_final<<<1, 1, 0, stream>>>(acc, out);
}

// Round 9
// 45.849 us; speedup vs baseline: 3.5967x; 3.5967x over previous
//
#include <hip/hip_runtime.h>
#include <hip/hip_bf16.h>
#include <float.h>

// RigidityLoss: M=16384 gathered points, brute-force KNN (K=8) + loss.
// R8: single fused KNN+merge+loss kernel.
//  Stage 1 (per block = 32 rows x 8 wave-splits): 32x32x16 f16 MFMA computes
//   t[r][c] = sq_c - 2*dot(q_r,p_c) (sq folded via k=3). Software-pipelined
//   b-loads (next tile in flight over current MFMA). Top-1 packed key
//   (dist-high-bits | cand idx) per (row, cls, split) bin -> LDS bins
//   [32][257] (no global traffic).
//  Stage 2 (same block, after barrier): 16 lanes/row scan 16 bins each
//   (top-2/lane), 8-round shfl extraction of global top-8, then the loss
//   terms with exact f32 d2 recompute. 2 atomics per block.

#define MPTS 16384
#define KNN  8
#define CDIM 16
#define LAMW 0.1f
#define EPSV 1e-6f

#define ROWS   32              // rows per block (one 32x32 MFMA row-tile)
#define NSPLIT 8               // waves per block = candidate splits
#define CSPL   (MPTS/NSPLIT)   // 2048 candidates per split
#define NT     (CSPL/32)       // 64 MFMA tiles per wave
#define BSTR   257             // padded LDS bin-row stride (words)

#define MED3 __builtin_amdgcn_fmed3f
typedef __attribute__((ext_vector_type(8)))  _Float16 f16x8;
typedef __attribute__((ext_vector_type(16))) float    f32x16;

__global__ __launch_bounds__(256) void k_gather(
    const float* __restrict__ canon, const float* __restrict__ trans,
    const int* __restrict__ indice, float4* __restrict__ c4,
    _Float16* __restrict__ bf16b, _Float16* __restrict__ af16b,
    float* __restrict__ acc)
{
    int t = blockIdx.x * 256 + threadIdx.x;
    if (t == 0) { acc[0] = 0.f; acc[1] = 0.f; }
    if (t < MPTS) {
        int j = indice[t];
        float x = canon[3*j+0] + trans[3*j+0];
        float y = canon[3*j+1] + trans[3*j+1];
        float z = canon[3*j+2] + trans[3*j+2];
        float sq = fmaf(x, x, fmaf(y, y, z*z));
        c4[t] = make_float4(-2.f*x, -2.f*y, -2.f*z, sq);   // exact f32 blob
        f16x8 aa = {};
        aa[0] = (_Float16)(-2.f*x); aa[1] = (_Float16)(-2.f*y);
        aa[2] = (_Float16)(-2.f*z); aa[3] = (_Float16)1.0f;
        *(f16x8*)(af16b + (size_t)t*8) = aa;
        f16x8 bb = {};
        bb[0] = (_Float16)x; bb[1] = (_Float16)y; bb[2] = (_Float16)z;
        bb[3] = (_Float16)sq;
        *(f16x8*)(bf16b + (size_t)t*8) = bb;
    }
}

__global__ __launch_bounds__(512, 8) void k_knn_loss(
    const float4* __restrict__ c4,
    const _Float16* __restrict__ bf16b, const _Float16* __restrict__ af16b,
    const int* __restrict__ indice, const float* __restrict__ motion,
    const float* __restrict__ fdc, float* __restrict__ acc)
{
    __shared__ float bins[ROWS * BSTR];      // 32.9 KB
    __shared__ float rS[NSPLIT], rM[NSPLIT];

    const int tid  = threadIdx.x;
    const int lane = tid & 63;
    const int wv   = tid >> 6;               // wave = candidate split 0..7
    const int rowbase = blockIdx.x * ROWS;
    const int cls  = lane & 31;
    const int cbeg = wv * CSPL;

    // A fragment: lane l<32 -> row (rowbase+l), k=0..7; lanes>=32 (k=8..15) zero.
    f16x8 afrag = *(const f16x8*)(af16b + (size_t)(rowbase + cls) * 8);
    if (lane >= 32) { f16x8 zz = {}; afrag = zz; }
    f32x16 zero16 = {};

    const _Float16* bptr  = bf16b + (size_t)(cbeg + cls) * 8;
    const unsigned  HMASK = 0xFFFFC000u;
    const unsigned  ivb   = (unsigned)(cbeg + cls);

    // 16 row-states (g -> row (g&3)+8*(g>>2)+4*(lane>>5)), top-1 each
    float e0=FLT_MAX,e1=FLT_MAX,e2=FLT_MAX,e3=FLT_MAX;
    float e4=FLT_MAX,e5=FLT_MAX,e6=FLT_MAX,e7=FLT_MAX;
    float e8=FLT_MAX,e9=FLT_MAX,e10=FLT_MAX,e11=FLT_MAX;
    float e12=FLT_MAX,e13=FLT_MAX,e14=FLT_MAX,e15=FLT_MAX;

    // software-pipelined tile loop: next b-load in flight over current MFMA
    f16x8 b = *(const f16x8*)(bptr);
    #pragma unroll 2
    for (int tile = 0; tile < NT; ++tile) {
        f16x8 bn = *(const f16x8*)(bptr + (size_t)(((tile + 1) & (NT-1)) * 256));
        f32x16 dv = __builtin_amdgcn_mfma_f32_32x32x16_f16(afrag, b, zero16, 0, 0, 0);
        unsigned iv = ivb + (unsigned)(tile * 32);
#define STEP(G, EG) { float kf = __uint_as_float((__float_as_uint(dv[G]) & HMASK) | iv); \
                      EG = fminf(EG, kf); }
        STEP(0,e0)   STEP(1,e1)   STEP(2,e2)   STEP(3,e3)
        STEP(4,e4)   STEP(5,e5)   STEP(6,e6)   STEP(7,e7)
        STEP(8,e8)   STEP(9,e9)   STEP(10,e10) STEP(11,e11)
        STEP(12,e12) STEP(13,e13) STEP(14,e14) STEP(15,e15)
#undef STEP
        b = bn;
    }

    // dump 16 bins to LDS: bins[rowL][wv*32 + cls], rowL = ST-row + (lane>>5)*4
    {
        float* bb = &bins[((lane >> 5) * 4) * BSTR + wv * 32 + cls];
#define ST(RO, EG) bb[(RO) * BSTR] = EG;
        ST(0,e0)   ST(1,e1)   ST(2,e2)   ST(3,e3)
        ST(8,e4)   ST(9,e5)   ST(10,e6)  ST(11,e7)
        ST(16,e8)  ST(17,e9)  ST(18,e10) ST(19,e11)
        ST(24,e12) ST(25,e13) ST(26,e14) ST(27,e15)
#undef ST
    }
    __syncthreads();

    // ---- merge: wave wv owns rows 4wv..4wv+3; 16 lanes per row ----
    const int sr = lane >> 4;                // sub-row 0..3
    const int lr = lane & 15;                // lane within row group
    const int rl = wv * 4 + sr;              // row-local 0..31
    const int row = rowbase + rl;

    // per-lane top-2 over its 16 bins (stride-16 so banks differ per lane)
    float g0 = FLT_MAX, g1 = FLT_MAX;
    #pragma unroll
    for (int i = 0; i < 16; ++i) {
        float v = bins[rl * BSTR + i * 16 + lr];
        g1 = MED3(g0, g1, v);
        g0 = fminf(g0, v);
    }

    // extract 8 smallest among the 16 lanes x top-2; lane s ends with s-th
    float kres = FLT_MAX;
    #pragma unroll
    for (int s = 0; s < KNN; ++s) {
        float m = g0;
        m = fminf(m, __shfl_xor(m, 1));
        m = fminf(m, __shfl_xor(m, 2));
        m = fminf(m, __shfl_xor(m, 4));
        m = fminf(m, __shfl_xor(m, 8));
        bool mine = (g0 == m);               // keys unique (idx in low bits)
        kres = (lr == s) ? m : kres;
        g0 = mine ? g1 : g0;
        g1 = mine ? FLT_MAX : g1;
    }

    // ---- loss: lanes lr<8 handle neighbors 0..7 of row rl ----
    float4 rc = c4[row];
    const float qx=-0.5f*rc.x, qy=-0.5f*rc.y, qz=-0.5f*rc.z, qq=rc.w;

    int jk = (int)(__float_as_uint(kres) & 0x3FFFu);
    float4 nc = c4[jk];
    float te  = fmaf(qx, nc.x, fmaf(qy, nc.y, fmaf(qz, nc.z, nc.w)));
    float d2k = qq + te;                     // exact squared distance

    // neighbor-coordinate sums over lanes lr 0..7 (xor 1,2,4 stays in 8-group)
    float xn = (lr < KNN) ? -0.5f*nc.x : 0.f;
    float yn = (lr < KNN) ? -0.5f*nc.y : 0.f;
    float zn = (lr < KNN) ? -0.5f*nc.z : 0.f;
    float sx = xn, sy = yn, sz = zn;
    sx += __shfl_xor(sx, 1); sx += __shfl_xor(sx, 2); sx += __shfl_xor(sx, 4);
    sy += __shfl_xor(sy, 1); sy += __shfl_xor(sy, 2); sy += __shfl_xor(sy, 4);
    sz += __shfl_xor(sz, 1); sz += __shfl_xor(sz, 2); sz += __shfl_xor(sz, 4);

    float surf = 0.f, simv = 0.f;
    if (lr < KNN) {
        if (lr == 0) {
            float dx = qx - sx * 0.125f + EPSV;
            float dy = qy - sy * 0.125f + EPSV;
            float dz = qz - sz * 0.125f + EPSV;
            surf = sqrtf(fmaf(dx, dx, fmaf(dy, dy, dz * dz)));
        }
        int irow = indice[row];
        int inb  = indice[jk];
        float c0v = fdc[3*irow+0] - fdc[3*inb+0] + EPSV;
        float c1v = fdc[3*irow+1] - fdc[3*inb+1] + EPSV;
        float c2v = fdc[3*irow+2] - fdc[3*inb+2] + EPSV;
        float cd2 = fmaf(c0v, c0v, fmaf(c1v, c1v, c2v * c2v));
        float w = __expf(-LAMW * fmaf(d2k, d2k, cd2));   // dist_w * color_w

        const float4* mr4 = (const float4*)(motion + CDIM * irow);
        const float4* mn4 = (const float4*)(motion + CDIM * inb);
        float s = 0.f;
        #pragma unroll
        for (int c = 0; c < CDIM/4; ++c) {
            float4 A = mr4[c], B = mn4[c];
            float h0 = A.x-B.x+EPSV, h1 = A.y-B.y+EPSV;
            float h2 = A.z-B.z+EPSV, h3 = A.w-B.w+EPSV;
            s = fmaf(h0,h0, fmaf(h1,h1, fmaf(h2,h2, fmaf(h3,h3, s))));
        }
        simv = w * sqrtf(s);
    }

    // ---- wave + block reduction ----
    float aS = surf, aM = simv;
    #pragma unroll
    for (int m = 1; m <= 32; m <<= 1) {
        aS += __shfl_xor(aS, m);
        aM += __shfl_xor(aM, m);
    }
    if (lane == 0) { rS[wv] = aS; rM[wv] = aM; }
    __syncthreads();
    if (tid == 0) {
        float tS = 0.f, tM = 0.f;
        #pragma unroll
        for (int w2 = 0; w2 < NSPLIT; ++w2) { tS += rS[w2]; tM += rM[w2]; }
        atomicAdd(&acc[0], tS);
        atomicAdd(&acc[1], tM);
    }
}

__global__ void k_final(const float* __restrict__ acc, float* __restrict__ out)
{
    out[0] = acc[0] * (1.0f / MPTS) + acc[1] * (1.0f / (MPTS * KNN));
}

extern "C" void kernel_launch(void* const* d_in, const int* in_sizes, int n_in,
                              void* d_out, int out_size, void* d_ws, size_t ws_size,
                              hipStream_t stream)
{
    const float* canon  = (const float*)d_in[0];
    const float* trans  = (const float*)d_in[1];
    const float* motion = (const float*)d_in[2];
    const float* fdc    = (const float*)d_in[3];
    const int*   indice = (const int*)d_in[4];
    float* out = (float*)d_out;

    char* ws = (char*)d_ws;
    float*     acc   = (float*)ws;                          // @0
    float4*    c4    = (float4*)(ws + 4096);                // 256 KB
    _Float16*  af16b = (_Float16*)(ws + 4096 + 262144);     // 256 KB
    _Float16*  bf16b = (_Float16*)(ws + 4096 + 2*262144);   // 256 KB

    k_gather<<<MPTS/256, 256, 0, stream>>>(canon, trans, indice, c4, bf16b, af16b, acc);
    k_knn_loss<<<MPTS/ROWS, 512, 0, stream>>>(c4, bf16b, af16b, indice, motion, fdc, acc);
    k_final<<<1, 1, 0, stream>>>(acc, out);
}

// Round 10
// 42.864 us; speedup vs baseline: 3.8471x; 1.0696x over previous
//
#include <hip/hip_runtime.h>
#include <hip/hip_bf16.h>
#include <float.h>

// RigidityLoss: M=16384 gathered points, brute-force KNN (K=8) + loss.
// R9: R8's fused MFMA+LDS-bin structure, candidate axis split x2 across
// blocks to fix grid-capped occupancy (R8: 512 blocks = 2/CU = latency-bound
// at VALUBusy 29%). Grid = 512 rowtiles x 2 halves = 1024 blocks (4/CU,
// 32 waves/CU). Per block: 8 waves x 1024 cands, 32x32x16 f16 MFMA
// (t = sq_c - 2 dot, sq folded via k=3), top-1 packed key per
// (row, cls, split) bin -> LDS bins[32][257], in-block 16-lane/row merge
// -> sorted top-8 of the half -> keys[half][row][8] (1 MB).
// k_merge_loss (R5-verified): exact two-pointer merge of the two sorted
// 8-lists per row + loss terms with exact f32 d2 recompute.

#define MPTS 16384
#define KNN  8
#define CDIM 16
#define LAMW 0.1f
#define EPSV 1e-6f

#define ROWS   32              // rows per block (one 32x32 MFMA row-tile)
#define NSPLIT 8               // waves per block = candidate splits
#define CSPL   1024            // candidates per split (half / 8 waves)
#define NT     (CSPL/32)       // 32 MFMA tiles per wave
#define BSTR   257             // padded LDS bin-row stride (words)

#define MED3 __builtin_amdgcn_fmed3f
typedef __attribute__((ext_vector_type(8)))  _Float16 f16x8;
typedef __attribute__((ext_vector_type(16))) float    f32x16;

__global__ __launch_bounds__(256) void k_gather(
    const float* __restrict__ canon, const float* __restrict__ trans,
    const int* __restrict__ indice, float4* __restrict__ c4,
    _Float16* __restrict__ bf16b, _Float16* __restrict__ af16b,
    float* __restrict__ acc)
{
    int t = blockIdx.x * 256 + threadIdx.x;
    if (t == 0) { acc[0] = 0.f; acc[1] = 0.f; }
    if (t < MPTS) {
        int j = indice[t];
        float x = canon[3*j+0] + trans[3*j+0];
        float y = canon[3*j+1] + trans[3*j+1];
        float z = canon[3*j+2] + trans[3*j+2];
        float sq = fmaf(x, x, fmaf(y, y, z*z));
        c4[t] = make_float4(-2.f*x, -2.f*y, -2.f*z, sq);   // exact f32 blob
        f16x8 aa = {};
        aa[0] = (_Float16)(-2.f*x); aa[1] = (_Float16)(-2.f*y);
        aa[2] = (_Float16)(-2.f*z); aa[3] = (_Float16)1.0f;
        *(f16x8*)(af16b + (size_t)t*8) = aa;
        f16x8 bb = {};
        bb[0] = (_Float16)x; bb[1] = (_Float16)y; bb[2] = (_Float16)z;
        bb[3] = (_Float16)sq;
        *(f16x8*)(bf16b + (size_t)t*8) = bb;
    }
}

__global__ __launch_bounds__(512, 8) void k_knn(
    const _Float16* __restrict__ bf16b, const _Float16* __restrict__ af16b,
    float* __restrict__ keys)
{
    __shared__ float bins[ROWS * BSTR];      // 32.9 KB

    const int tid  = threadIdx.x;
    const int lane = tid & 63;
    const int wv   = tid >> 6;               // wave = candidate split 0..7
    const int half = blockIdx.x & 1;
    const int rowbase = (blockIdx.x >> 1) * ROWS;
    const int cls  = lane & 31;
    const int cbeg = half * (MPTS/2) + wv * CSPL;

    // A fragment: lane l<32 -> row (rowbase+l), k=0..7; lanes>=32 (k=8..15) zero.
    f16x8 afrag = *(const f16x8*)(af16b + (size_t)(rowbase + cls) * 8);
    if (lane >= 32) { f16x8 zz = {}; afrag = zz; }
    f32x16 zero16 = {};

    const _Float16* bptr  = bf16b + (size_t)(cbeg + cls) * 8;
    const unsigned  HMASK = 0xFFFFC000u;
    const unsigned  ivb   = (unsigned)(cbeg + cls);

    // 16 row-states (g -> row (g&3)+8*(g>>2)+4*(lane>>5)), top-1 each
    float e0=FLT_MAX,e1=FLT_MAX,e2=FLT_MAX,e3=FLT_MAX;
    float e4=FLT_MAX,e5=FLT_MAX,e6=FLT_MAX,e7=FLT_MAX;
    float e8=FLT_MAX,e9=FLT_MAX,e10=FLT_MAX,e11=FLT_MAX;
    float e12=FLT_MAX,e13=FLT_MAX,e14=FLT_MAX,e15=FLT_MAX;

    // software-pipelined tile loop: next b-load in flight over current MFMA
    f16x8 b = *(const f16x8*)(bptr);
    #pragma unroll 2
    for (int tile = 0; tile < NT; ++tile) {
        f16x8 bn = *(const f16x8*)(bptr + (size_t)(((tile + 1) & (NT-1)) * 256));
        f32x16 dv = __builtin_amdgcn_mfma_f32_32x32x16_f16(afrag, b, zero16, 0, 0, 0);
        unsigned iv = ivb + (unsigned)(tile * 32);
#define STEP(G, EG) { float kf = __uint_as_float((__float_as_uint(dv[G]) & HMASK) | iv); \
                      EG = fminf(EG, kf); }
        STEP(0,e0)   STEP(1,e1)   STEP(2,e2)   STEP(3,e3)
        STEP(4,e4)   STEP(5,e5)   STEP(6,e6)   STEP(7,e7)
        STEP(8,e8)   STEP(9,e9)   STEP(10,e10) STEP(11,e11)
        STEP(12,e12) STEP(13,e13) STEP(14,e14) STEP(15,e15)
#undef STEP
        b = bn;
    }

    // dump 16 bins to LDS: bins[rowL][wv*32 + cls], rowL = ST-row + (lane>>5)*4
    {
        float* bb = &bins[((lane >> 5) * 4) * BSTR + wv * 32 + cls];
#define ST(RO, EG) bb[(RO) * BSTR] = EG;
        ST(0,e0)   ST(1,e1)   ST(2,e2)   ST(3,e3)
        ST(8,e4)   ST(9,e5)   ST(10,e6)  ST(11,e7)
        ST(16,e8)  ST(17,e9)  ST(18,e10) ST(19,e11)
        ST(24,e12) ST(25,e13) ST(26,e14) ST(27,e15)
#undef ST
    }
    __syncthreads();

    // ---- merge: wave wv owns rows 4wv..4wv+3; 16 lanes per row ----
    const int sr = lane >> 4;                // sub-row 0..3
    const int lr = lane & 15;                // lane within row group
    const int rl = wv * 4 + sr;              // row-local 0..31
    const int row = rowbase + rl;

    // per-lane top-2 over its 16 bins
    float g0 = FLT_MAX, g1 = FLT_MAX;
    #pragma unroll
    for (int i = 0; i < 16; ++i) {
        float v = bins[rl * BSTR + i * 16 + lr];
        g1 = MED3(g0, g1, v);
        g0 = fminf(g0, v);
    }

    // extract 8 smallest among the 16 lanes x top-2; lane s ends with s-th
    float kres = FLT_MAX;
    #pragma unroll
    for (int s = 0; s < KNN; ++s) {
        float m = g0;
        m = fminf(m, __shfl_xor(m, 1));
        m = fminf(m, __shfl_xor(m, 2));
        m = fminf(m, __shfl_xor(m, 4));
        m = fminf(m, __shfl_xor(m, 8));
        bool mine = (g0 == m);               // keys unique (idx in low bits)
        kres = (lr == s) ? m : kres;
        g0 = mine ? g1 : g0;
        g1 = mine ? FLT_MAX : g1;
    }

    if (lr < KNN)
        keys[((size_t)half * MPTS + row) * KNN + lr] = kres;   // sorted list
}

__global__ __launch_bounds__(256) void k_merge_loss(
    const float4* __restrict__ c4, const float* __restrict__ keys,
    const int* __restrict__ indice, const float* __restrict__ motion,
    const float* __restrict__ fdc, float* __restrict__ acc)
{
    __shared__ float rS[4], rM[4];
    const int tid  = threadIdx.x;
    const int lane = tid & 63;
    const int wv   = tid >> 6;
    const int row  = blockIdx.x * 256 + tid;

    // two sorted 8-lists (named regs; fully static)
    const float4* pa4 = (const float4*)(keys + (size_t)row * KNN);
    const float4* pb4 = (const float4*)(keys + ((size_t)MPTS + row) * KNN);
    float4 A0 = pa4[0], A1 = pa4[1], B0 = pb4[0], B1 = pb4[1];
    float a0=A0.x,a1=A0.y,a2=A0.z,a3=A0.w,a4=A1.x,a5=A1.y,a6=A1.z,a7=A1.w;
    float b0=B0.x,b1=B0.y,b2=B0.z,b3=B0.w,b4=B1.x,b5=B1.y,b6=B1.z,b7=B1.w;

    float4 rc = c4[row];
    const float qx=-0.5f*rc.x, qy=-0.5f*rc.y, qz=-0.5f*rc.z, qq=rc.w;
    const int irow = indice[row];
    const float f0 = fdc[3*irow+0], f1 = fdc[3*irow+1], f2 = fdc[3*irow+2];
    const float4* mr4 = (const float4*)(motion + CDIM * irow);
    float4 m0 = mr4[0], m1 = mr4[1], m2 = mr4[2], m3 = mr4[3];

    float sx = 0.f, sy = 0.f, sz = 0.f, simsum = 0.f;
    #pragma unroll
    for (int s = 0; s < KNN; ++s) {
        bool m = (a0 <= b0);
        float kk = m ? a0 : b0;
        // shift chosen list (all static-indexed)
        float na0=m?a1:a0, na1=m?a2:a1, na2=m?a3:a2, na3=m?a4:a3;
        float na4=m?a5:a4, na5=m?a6:a5, na6=m?a7:a6, na7=m?FLT_MAX:a7;
        float nb0=m?b0:b1, nb1=m?b1:b2, nb2=m?b2:b3, nb3=m?b3:b4;
        float nb4=m?b4:b5, nb5=m?b5:b6, nb6=m?b6:b7, nb7=m?b7:FLT_MAX;
        a0=na0;a1=na1;a2=na2;a3=na3;a4=na4;a5=na5;a6=na6;a7=na7;
        b0=nb0;b1=nb1;b2=nb2;b3=nb3;b4=nb4;b5=nb5;b6=nb6;b7=nb7;

        int jk = (int)(__float_as_uint(kk) & 0x3FFFu);
        float4 nc = c4[jk];
        // exact squared distance (same expanded form as reference)
        float te  = fmaf(qx, nc.x, fmaf(qy, nc.y, fmaf(qz, nc.z, nc.w)));
        float d2k = qq + te;
        sx += -0.5f*nc.x; sy += -0.5f*nc.y; sz += -0.5f*nc.z;

        int inb = indice[jk];
        float c0v = f0 - fdc[3*inb+0] + EPSV;
        float c1v = f1 - fdc[3*inb+1] + EPSV;
        float c2v = f2 - fdc[3*inb+2] + EPSV;
        float cd2 = fmaf(c0v, c0v, fmaf(c1v, c1v, c2v * c2v));
        float w = __expf(-LAMW * fmaf(d2k, d2k, cd2));  // dist_w * color_w fused

        const float4* mn4 = (const float4*)(motion + CDIM * inb);
        float4 u0 = mn4[0], u1 = mn4[1], u2 = mn4[2], u3 = mn4[3];
        float sacc = 0.f;
#define MD(A,B) { float g0v=A.x-B.x+EPSV, g1v=A.y-B.y+EPSV,               \
                        g2v=A.z-B.z+EPSV, g3v=A.w-B.w+EPSV;               \
                  sacc = fmaf(g0v,g0v,fmaf(g1v,g1v,fmaf(g2v,g2v,fmaf(g3v,g3v,sacc)))); }
        MD(m0,u0) MD(m1,u1) MD(m2,u2) MD(m3,u3)
#undef MD
        simsum += w * sqrtf(sacc);
    }

    float dx = qx - sx * 0.125f + EPSV;
    float dy = qy - sy * 0.125f + EPSV;
    float dz = qz - sz * 0.125f + EPSV;
    float surf = sqrtf(fmaf(dx, dx, fmaf(dy, dy, dz * dz)));

    // ---- block reduction ----
    float aS = surf, aM = simsum;
    #pragma unroll
    for (int m = 1; m <= 32; m <<= 1) {
        aS += __shfl_xor(aS, m);
        aM += __shfl_xor(aM, m);
    }
    if (lane == 0) { rS[wv] = aS; rM[wv] = aM; }
    __syncthreads();
    if (tid == 0) {
        float tS = 0.f, tM = 0.f;
        #pragma unroll
        for (int w2 = 0; w2 < 4; ++w2) { tS += rS[w2]; tM += rM[w2]; }
        atomicAdd(&acc[0], tS);
        atomicAdd(&acc[1], tM);
    }
}

__global__ void k_final(const float* __restrict__ acc, float* __restrict__ out)
{
    out[0] = acc[0] * (1.0f / MPTS) + acc[1] * (1.0f / (MPTS * KNN));
}

extern "C" void kernel_launch(void* const* d_in, const int* in_sizes, int n_in,
                              void* d_out, int out_size, void* d_ws, size_t ws_size,
                              hipStream_t stream)
{
    const float* canon  = (const float*)d_in[0];
    const float* trans  = (const float*)d_in[1];
    const float* motion = (const float*)d_in[2];
    const float* fdc    = (const float*)d_in[3];
    const int*   indice = (const int*)d_in[4];
    float* out = (float*)d_out;

    char* ws = (char*)d_ws;
    float*     acc   = (float*)ws;                          // @0
    float4*    c4    = (float4*)(ws + 4096);                // 256 KB
    _Float16*  af16b = (_Float16*)(ws + 4096 + 262144);     // 256 KB
    _Float16*  bf16b = (_Float16*)(ws + 4096 + 2*262144);   // 256 KB
    float*     keys  = (float*)(ws + 4096 + 3*262144);      // 2*M*8*4 = 1 MB

    k_gather<<<MPTS/256, 256, 0, stream>>>(canon, trans, indice, c4, bf16b, af16b, acc);
    k_knn<<<(MPTS/ROWS)*2, 512, 0, stream>>>(bf16b, af16b, keys);
    k_merge_loss<<<MPTS/256, 256, 0, stream>>>(c4, keys, indice, motion, fdc, acc);
    k_final<<<1, 1, 0, stream>>>(acc, out);
}